// Round 10
// baseline (3169.451 us; speedup 1.0000x reference)
//
#include <hip/hip_runtime.h>
#include <hip/hip_bf16.h>
#include <math.h>

// Shapes
#define N_TRAIN 4096
#define N_FEAT  64
#define N_HID   256
#define ENC     256
#define N_ANTES 2048
#define ATT_H   256
#define MAX_LEN 16

typedef unsigned int u32;
typedef unsigned short u16;
typedef short short8 __attribute__((ext_vector_type(8)));
typedef float floatx16 __attribute__((ext_vector_type(16)));

__device__ __forceinline__ float fsig(float x)  { return 1.f / (1.f + __expf(-x)); }
__device__ __forceinline__ float ftanh(float x) { return 2.f / (1.f + __expf(-2.f * x)) - 1.f; }

// bf16 round-to-nearest-even helpers
__device__ __forceinline__ u16 f2bf(float x) {
    u32 b = __float_as_uint(x);
    return (u16)((b + 0x7FFFu + ((b >> 16) & 1u)) >> 16);
}
__device__ __forceinline__ float bf2f(u16 h) {
    return __uint_as_float(((u32)h) << 16);
}
// cheap truncation hi/lo split (residual v-hi exact in fp32)
__device__ __forceinline__ void split_bf(float v, u16& hi, u16& lo) {
    u32 b = __float_as_uint(v);
    hi = (u16)(b >> 16);
    float r = v - __uint_as_float(b & 0xFFFF0000u);
    lo = (u16)(__float_as_uint(r) >> 16);
}

// A/B fragment k-offset for v_mfma_f32_32x32x16_bf16 (2xK stacked CDNA layout):
// lane l, elem j (0..7) -> k = 4*(l>>5) + (j&3) + 8*(j>>2)
__device__ __forceinline__ int kin_of(int l, int j) {
    return ((l >> 5) << 2) + (j & 3) + ((j >> 2) << 3);
}

// ---------------------------------------------------------------------------
// Tiled GEMM: C[m,n] = act(bias[n] + sum_k A[m,k] * B[n,k]); 64x64x16 tiles.
// (encoder only)
// ---------------------------------------------------------------------------
template <bool RELU>
__global__ __launch_bounds__(256) void gemm_abT(
    const float* __restrict__ A, const float* __restrict__ B,
    const float* __restrict__ bias, float* __restrict__ C,
    int M, int N, int K, int lda, int ldb, int ldc)
{
    __shared__ __align__(16) float As[16][68];
    __shared__ __align__(16) float Bs[16][68];
    const int tid = threadIdx.x;
    const int m0 = blockIdx.x * 64, n0 = blockIdx.y * 64;
    const int tx = tid & 15, ty = tid >> 4;
    const int kl = tid & 15, rl = tid >> 4;
    float acc[4][4] = {};

    for (int k0 = 0; k0 < K; k0 += 16) {
        #pragma unroll
        for (int pp = 0; pp < 4; ++pp) {
            int r = rl + pp * 16;
            As[kl][r] = A[(size_t)(m0 + r) * lda + k0 + kl];
            Bs[kl][r] = B[(size_t)(n0 + r) * ldb + k0 + kl];
        }
        __syncthreads();
        #pragma unroll
        for (int k = 0; k < 16; ++k) {
            float4 av = *(const float4*)&As[k][ty * 4];
            float4 bv = *(const float4*)&Bs[k][tx * 4];
            float a4[4] = {av.x, av.y, av.z, av.w};
            float b4[4] = {bv.x, bv.y, bv.z, bv.w};
            #pragma unroll
            for (int i = 0; i < 4; ++i)
                #pragma unroll
                for (int j = 0; j < 4; ++j)
                    acc[i][j] = fmaf(a4[i], b4[j], acc[i][j]);
        }
        __syncthreads();
    }
    #pragma unroll
    for (int i = 0; i < 4; ++i) {
        int m = m0 + ty * 4 + i;
        #pragma unroll
        for (int j = 0; j < 4; ++j) {
            int n = n0 + tx * 4 + j;
            float v = acc[i][j] + bias[n];
            if (RELU) v = fmaxf(v, 0.f);
            C[(size_t)m * ldc + n] = v;
        }
    }
}

// ---------------------------------------------------------------------------
// rowsum[j] = sum_k w_ih[j, k]
// ---------------------------------------------------------------------------
__global__ __launch_bounds__(256) void k_rowsum(const float* __restrict__ w_ih,
                                                float* __restrict__ rowsum)
{
    __shared__ float red[256];
    const int j = blockIdx.x, tid = threadIdx.x;
    float s = 0.f;
    for (int i = tid; i < N_ANTES; i += 256) s += w_ih[(size_t)j * N_ANTES + i];
    red[tid] = s; __syncthreads();
    for (int off = 128; off > 0; off >>= 1) {
        if (tid < off) red[tid] += red[tid + off];
        __syncthreads();
    }
    if (tid == 0) rowsum[j] = red[0];
}

// ---------------------------------------------------------------------------
// WbT[k*256 + j] = att_w1[j*(N_TRAIN+ENC) + N_TRAIN + k]
// ---------------------------------------------------------------------------
__global__ __launch_bounds__(256) void k_wbT(const float* __restrict__ att_w1,
                                             float* __restrict__ WbT)
{
    int gid = blockIdx.x * 256 + threadIdx.x;  // 0..65535
    int j = gid >> 8, k = gid & 255;
    WbT[(size_t)k * 256 + j] = att_w1[(size_t)j * (N_TRAIN + ENC) + N_TRAIN + k];
}

// ---------------------------------------------------------------------------
// Pack Wa = att_w1[:, :N_TRAIN] (256x4096) into A-fragment order (bf16 hi/lo).
// ---------------------------------------------------------------------------
__global__ __launch_bounds__(256) void k_packAf(const float* __restrict__ att_w1,
                                                u16* __restrict__ Af_hi,
                                                u16* __restrict__ Af_lo)
{
    int gid = blockIdx.x * 256 + threadIdx.x;   // 0..1048575
    int j  = gid & 7;
    int l  = (gid >> 3) & 63;
    int kt = (gid >> 9) & 255;
    int mt = gid >> 17;
    int m = mt * 32 + (l & 31);
    int k = kt * 16 + kin_of(l, j);
    float v = att_w1[(size_t)m * (N_TRAIN + ENC) + k];
    u16 hi, lo; split_bf(v, hi, lo);
    Af_hi[gid] = hi;
    Af_lo[gid] = lo;
}

// ---------------------------------------------------------------------------
// preT = Wa @ S via MFMA bf16x3, split-K=8. Grid (8 kz, 32 np, 4 mq), 256 thr.
// Paired K-chunks (kz, kz+4) accumulate into buffer kz&3 via atomicAdd on
// pre-zeroed P: exactly 2 commutative fp32 adds -> deterministic.
// ---------------------------------------------------------------------------
#define PSPLIT 8
__global__ __launch_bounds__(256) void k_gemm_preT(
    const u16* __restrict__ Af_hi, const u16* __restrict__ Af_lo,
    const float* __restrict__ S, float* __restrict__ P)
{
    const int tid = threadIdx.x, lane = tid & 63, w = tid >> 6;
    const int kz = blockIdx.x;          // 0..7
    const int np = blockIdx.y;          // 0..31
    const int mq = blockIdx.z;          // 0..3
    const int mt = mq * 2 + (w & 1);    // 0..7
    const int ni = w >> 1;              // 0..1
    const int nb = np * 64 + ni * 32 + (lane & 31);
    const int kb = 4 * (lane >> 5);
    floatx16 acc = {0,0,0,0,0,0,0,0,0,0,0,0,0,0,0,0};

    const int kt_beg = kz * 32, kt_end = kt_beg + 32;
    #pragma unroll 4
    for (int kt = kt_beg; kt < kt_end; ++kt) {
        size_t ao = (((size_t)mt * 256 + kt) * 64 + lane) * 8;
        short8 ahi = *(const short8*)(Af_hi + ao);
        short8 alo = *(const short8*)(Af_lo + ao);
        short8 bhi, blo;
        #pragma unroll
        for (int j = 0; j < 8; ++j) {
            int k = kt * 16 + kb + (j & 3) + 8 * (j >> 2);
            float v = S[(size_t)k * N_ANTES + nb];
            u16 hi, lo; split_bf(v, hi, lo);
            bhi[j] = (short)hi;
            blo[j] = (short)lo;
        }
        acc = __builtin_amdgcn_mfma_f32_32x32x16_bf16(ahi, bhi, acc, 0, 0, 0);
        acc = __builtin_amdgcn_mfma_f32_32x32x16_bf16(ahi, blo, acc, 0, 0, 0);
        acc = __builtin_amdgcn_mfma_f32_32x32x16_bf16(alo, bhi, acc, 0, 0, 0);
    }

    float* Pk = P + (size_t)(kz & 3) * (ATT_H * N_ANTES);
    #pragma unroll
    for (int q = 0; q < 16; ++q) {
        int row = mt * 32 + (q & 3) + 8 * (q >> 2) + 4 * (lane >> 5);
        atomicAdd(&Pk[(size_t)row * N_ANTES + nb], acc[q]);
    }
}

__global__ __launch_bounds__(256) void k_reduce4(const float* __restrict__ P,
                                                 float* __restrict__ preT)
{
    int gid = blockIdx.x * 256 + threadIdx.x;
    const int SZ = ATT_H * N_ANTES;
    preT[gid] = (P[gid] + P[gid + SZ]) + (P[gid + 2 * SZ] + P[gid + 3 * SZ]);
}

// ---------------------------------------------------------------------------
// Pack w_hh into B-fragment order (bf16 hi/lo), gate-interleaved columns.
// ---------------------------------------------------------------------------
__global__ __launch_bounds__(256) void k_packWf(const float* __restrict__ w_hh,
                                                u16* __restrict__ Wf_hi,
                                                u16* __restrict__ Wf_lo)
{
    int gid = blockIdx.x * 256 + threadIdx.x;      // 0..262143
    int j    = gid & 7;
    int l    = (gid >> 3) & 63;
    int kt   = (gid >> 9) & 15;
    int nsub = (gid >> 13) & 1;
    int cb   = gid >> 14;
    int k  = kt * 16 + kin_of(l, j);
    int cc = nsub * 32 + (l & 31);
    int jj = cb * 16 + (cc >> 2);
    int g  = cc & 3;
    int J  = g * 256 + jj;
    float v = w_hh[(size_t)J * 256 + k];
    u16 hi = f2bf(v);
    Wf_hi[gid] = hi;
    Wf_lo[gid] = f2bf(v - bf2f(hi));
}

// ---------------------------------------------------------------------------
// Pack fp32 h into A-fragment order (bf16 hi/lo).
// ---------------------------------------------------------------------------
__global__ __launch_bounds__(256) void k_packHf(const float* __restrict__ h,
                                                u16* __restrict__ Hf_hi,
                                                u16* __restrict__ Hf_lo)
{
    int gid = blockIdx.x * 256 + threadIdx.x;      // 0..1048575
    int j  = gid & 7;
    int l  = (gid >> 3) & 63;
    int kt = (gid >> 9) & 15;
    int mt = gid >> 13;
    int m = mt * 32 + (l & 31);
    int k = kt * 16 + kin_of(l, j);
    float v = h[(size_t)m * 256 + k];
    u16 hi = f2bf(v);
    Hf_hi[gid] = hi;
    Hf_lo[gid] = f2bf(v - bf2f(hi));
}

// ---------------------------------------------------------------------------
// Fused step kernel, 1088 blocks, __launch_bounds__(256,5) => 5 blocks/CU
// guaranteed => all 1088 co-resident (capacity 1280) => spin is deadlock-free.
//   blocks [0,64):    attention for step t-1 (exact k_att body; e_acc(t-1)
//                     complete via stream order). Last att block does softmax,
//                     writes out(t-1)/idx(t-1), resets cnt, releases flag[t].
//   blocks [64,1088): z-GEMM (R9 k_zgemm); epilogue spin-acquires flag[t]
//                     before reading idx(t-1) -- attention hides under MFMA.
// t=0: att blocks exit; gemm skips spin (a=1).
// ---------------------------------------------------------------------------
__global__ __launch_bounds__(256, 5) void k_step(
    const u16* __restrict__ Hf_hi_r, const u16* __restrict__ Hf_lo_r,
    u16* __restrict__ Hf_hi_w, u16* __restrict__ Hf_lo_w,
    const u16* __restrict__ Wf_hi, const u16* __restrict__ Wf_lo,
    float* __restrict__ c,
    const float* __restrict__ rowsum, const float* __restrict__ b_ih,
    const float* __restrict__ b_hh, const float* __restrict__ S,
    int* __restrict__ idx_buf, int t, float* __restrict__ e_acc_t,
    const float* __restrict__ e_acc_prev,
    const float* __restrict__ preT, const float* __restrict__ WbT,
    const float* __restrict__ att_b1, const float* __restrict__ att_w2,
    const float* __restrict__ att_b2, float* __restrict__ scores,
    float* __restrict__ out_prev, int* __restrict__ cnt,
    int* __restrict__ flag_t)
{
    __shared__ __align__(16) float z_lds[64][68];
    __shared__ float red[256];
    __shared__ float e_lds[256], u_s[256], w2s[256];
    __shared__ float smax[256], ssum[256];
    __shared__ int   sidx[256];
    __shared__ int   is_last, idxp_s;
    const int tid = threadIdx.x;

    if (blockIdx.x < 64) {
        // ================= attention for step t-1 =================
        if (t == 0) return;
        e_lds[tid] = e_acc_prev[tid] * (1.f / (float)N_TRAIN);
        w2s[tid] = att_w2[tid];
        __syncthreads();

        float uacc = att_b1[tid];
        for (int k = 0; k < 256; ++k)
            uacc = fmaf(e_lds[k], WbT[(size_t)k * 256 + tid], uacc);
        u_s[tid] = uacc;
        __syncthreads();

        const int pl = tid & 31, jq = tid >> 5;   // 8-way j split
        const int p = blockIdx.x * 32 + pl;
        float sc = 0.f;
        #pragma unroll 4
        for (int j = jq; j < 256; j += 8) {
            float v = preT[(size_t)j * N_ANTES + p] + u_s[j];
            sc = fmaf(fmaxf(v, 0.f), w2s[j], sc);
        }
        red[tid] = sc;
        __syncthreads();
        if (tid < 32) {
            float s = att_b2[0];
            #pragma unroll
            for (int q = 0; q < 8; ++q) s += red[tid + q * 32];
            scores[blockIdx.x * 32 + tid] = s;
        }

        __threadfence();
        __syncthreads();
        if (tid == 0)
            is_last = (atomicAdd(cnt, 1) == 63);
        __syncthreads();
        if (!is_last) return;
        __threadfence();

        float sv[8];
        #pragma unroll
        for (int i = 0; i < 8; ++i) sv[i] = scores[tid * 8 + i];

        float lmax = -INFINITY; int lidx = 0;
        #pragma unroll
        for (int i = 0; i < 8; ++i)
            if (sv[i] > lmax) { lmax = sv[i]; lidx = tid * 8 + i; }
        smax[tid] = lmax; sidx[tid] = lidx;
        __syncthreads();
        for (int off = 128; off > 0; off >>= 1) {
            if (tid < off) {
                float ov = smax[tid + off]; int oi = sidx[tid + off];
                if (ov > smax[tid] || (ov == smax[tid] && oi < sidx[tid])) {
                    smax[tid] = ov; sidx[tid] = oi;
                }
            }
            __syncthreads();
        }
        const float gmax = smax[0];
        const int gidx = sidx[0];

        float lsum = 0.f;
        #pragma unroll
        for (int i = 0; i < 8; ++i) lsum += __expf(sv[i] - gmax);
        ssum[tid] = lsum;
        __syncthreads();
        for (int off = 128; off > 0; off >>= 1) {
            if (tid < off) ssum[tid] += ssum[tid + off];
            __syncthreads();
        }
        const float lse = gmax + logf(ssum[0]);

        #pragma unroll
        for (int i = 0; i < 8; ++i)
            out_prev[tid * 8 + i] = sv[i] - lse;
        if (tid == 0) idx_buf[t - 1] = gidx;
        __syncthreads();
        __threadfence();
        if (tid == 0) {
            *cnt = 0;
            __hip_atomic_store(flag_t, 1, __ATOMIC_RELEASE,
                               __HIP_MEMORY_SCOPE_AGENT);
        }
        return;
    }

    // ================= z-GEMM (R9 k_zgemm body) =================
    const int g  = blockIdx.x - 64;
    const int rb = g >> 4;           // 0..63  (64 rows each)
    const int cb = g & 15;           // 0..15  (64 packed cols each)
    const int lane = tid & 63;
    const int w    = tid >> 6;       // 0..3
    const int mt = rb * 2 + (w & 1); // 0..127
    const int ni = w >> 1;           // 0..1

    floatx16 acc = {0,0,0,0,0,0,0,0,0,0,0,0,0,0,0,0};
    const size_t aoff = (size_t)mt * 16 * 512 + lane * 8;
    const size_t boff = (size_t)(cb * 2 + ni) * 16 * 512 + lane * 8;

    #pragma unroll 4
    for (int kt = 0; kt < 16; ++kt) {
        short8 ahi = *(const short8*)(Hf_hi_r + aoff + kt * 512);
        short8 alo = *(const short8*)(Hf_lo_r + aoff + kt * 512);
        short8 bhi = *(const short8*)(Wf_hi   + boff + kt * 512);
        short8 blo = *(const short8*)(Wf_lo   + boff + kt * 512);
        acc = __builtin_amdgcn_mfma_f32_32x32x16_bf16(ahi, bhi, acc, 0, 0, 0);
        acc = __builtin_amdgcn_mfma_f32_32x32x16_bf16(ahi, blo, acc, 0, 0, 0);
        acc = __builtin_amdgcn_mfma_f32_32x32x16_bf16(alo, bhi, acc, 0, 0, 0);
    }

    // C/D layout (HW-verified): col = lane&31, row = (q&3)+8*(q>>2)+4*(lane>>5)
    #pragma unroll
    for (int q = 0; q < 16; ++q) {
        int row = (w & 1) * 32 + (q & 3) + 8 * (q >> 2) + 4 * (lane >> 5);
        z_lds[row][ni * 32 + (lane & 31)] = acc[q];
    }

    // spin for idx(t-1) while attention (other blocks) finishes -- overlapped
    if (t > 0) {
        if (tid == 0) {
            while (__hip_atomic_load(flag_t, __ATOMIC_ACQUIRE,
                                     __HIP_MEMORY_SCOPE_AGENT) == 0)
                __builtin_amdgcn_s_sleep(2);
            idxp_s = idx_buf[t - 1];
        }
    }
    __syncthreads();

    // ---- fused gates: thread = (jj_l, rg) handles 4 rows of one enc-col ----
    const int jj_l = tid & 15, rg = tid >> 4;
    const int Jc = cb * 16 + jj_l;           // enc-dim column (0..255)
    float rs[4], bs[4];
    #pragma unroll
    for (int gg = 0; gg < 4; ++gg) {
        int J = gg * 256 + Jc;
        rs[gg] = rowsum[J];
        bs[gg] = b_ih[J] + b_hh[J];
    }
    const int idxp = (t > 0) ? idxp_s : 0;
    float esum = 0.f;
    #pragma unroll
    for (int p = 0; p < 4; ++p) {
        int r = rg * 4 + p;
        int rglob = rb * 64 + r;
        float a = (t > 0) ? S[(size_t)rglob * N_ANTES + idxp] : 1.f;
        float4 z4 = *(const float4*)&z_lds[r][jj_l * 4];
        float zi = z4.x + fmaf(a, rs[0], bs[0]);
        float zf = z4.y + fmaf(a, rs[1], bs[1]);
        float zg = z4.z + fmaf(a, rs[2], bs[2]);
        float zo = z4.w + fmaf(a, rs[3], bs[3]);
        size_t coff = (size_t)rglob * 256 + Jc;
        float cn = fsig(zf) * c[coff] + fsig(zi) * ftanh(zg);
        float hn = fsig(zo) * ftanh(cn);
        c[coff] = cn;
        esum += hn;
        // write h back in A-fragment order (inverse of kin_of; bijective)
        u16 hi = f2bf(hn);
        u16 lo = f2bf(hn - bf2f(hi));
        int mtw    = rglob >> 5;
        int lane_a = (rglob & 31) + 32 * ((Jc >> 2) & 1);
        int ktw    = Jc >> 4;
        int jw     = (Jc & 3) + ((Jc >> 3) & 1) * 4;
        size_t off = (((size_t)mtw * 16 + ktw) * 64 + lane_a) * 8 + jw;
        Hf_hi_w[off] = hi;
        Hf_lo_w[off] = lo;
    }
    red[tid] = esum;
    __syncthreads();
    if (tid < 16) {
        float s = 0.f;
        #pragma unroll
        for (int q = 0; q < 16; ++q) s += red[tid + q * 16];
        atomicAdd(&e_acc_t[Jc - jj_l + tid], s);   // = e_acc_t[cb*16 + tid]
    }
}

// ---------------------------------------------------------------------------
// Standalone attention (used once, for t = MAX_LEN-1).
// ---------------------------------------------------------------------------
__global__ __launch_bounds__(256) void k_att(
    const float* __restrict__ preT, const float* __restrict__ e_accum_t,
    const float* __restrict__ WbT, const float* __restrict__ att_b1,
    const float* __restrict__ att_w2, const float* __restrict__ att_b2,
    float* __restrict__ scores, float* __restrict__ out_t,
    int* __restrict__ idx_t, int* __restrict__ cnt)
{
    __shared__ float e_lds[256];
    __shared__ float u[256];
    __shared__ float w2s[256];
    __shared__ float red[256];
    const int tid = threadIdx.x;
    e_lds[tid] = e_accum_t[tid] * (1.f / (float)N_TRAIN);
    w2s[tid] = att_w2[tid];
    __syncthreads();

    float uacc = att_b1[tid];
    for (int k = 0; k < 256; ++k)
        uacc = fmaf(e_lds[k], WbT[(size_t)k * 256 + tid], uacc);
    u[tid] = uacc;
    __syncthreads();

    const int pl = tid & 31, jq = tid >> 5;   // 8-way j split
    const int p = blockIdx.x * 32 + pl;
    float sc = 0.f;
    #pragma unroll 4
    for (int j = jq; j < 256; j += 8) {
        float v = preT[(size_t)j * N_ANTES + p] + u[j];
        sc = fmaf(fmaxf(v, 0.f), w2s[j], sc);
    }
    red[tid] = sc;
    __syncthreads();
    if (tid < 32) {
        float s = att_b2[0];
        #pragma unroll
        for (int q = 0; q < 8; ++q) s += red[tid + q * 32];
        scores[blockIdx.x * 32 + tid] = s;
    }

    // ---- last-block handshake ----
    __threadfence();
    __syncthreads();
    __shared__ int is_last;
    if (tid == 0)
        is_last = (atomicAdd(cnt, 1) == (int)gridDim.x - 1);
    __syncthreads();
    if (!is_last) return;
    __threadfence();

    __shared__ float smax[256];
    __shared__ int   sidx[256];
    __shared__ float ssum[256];

    float sv[8];
    #pragma unroll
    for (int i = 0; i < 8; ++i) sv[i] = scores[tid * 8 + i];

    float lmax = -INFINITY; int lidx = 0;
    #pragma unroll
    for (int i = 0; i < 8; ++i)
        if (sv[i] > lmax) { lmax = sv[i]; lidx = tid * 8 + i; }
    smax[tid] = lmax; sidx[tid] = lidx;
    __syncthreads();
    for (int off = 128; off > 0; off >>= 1) {
        if (tid < off) {
            float ov = smax[tid + off]; int oi = sidx[tid + off];
            if (ov > smax[tid] || (ov == smax[tid] && oi < sidx[tid])) {
                smax[tid] = ov; sidx[tid] = oi;
            }
        }
        __syncthreads();
    }
    const float gmax = smax[0];
    const int gidx = sidx[0];

    float lsum = 0.f;
    #pragma unroll
    for (int i = 0; i < 8; ++i) lsum += __expf(sv[i] - gmax);
    ssum[tid] = lsum;
    __syncthreads();
    for (int off = 128; off > 0; off >>= 1) {
        if (tid < off) ssum[tid] += ssum[tid + off];
        __syncthreads();
    }
    const float lse = gmax + logf(ssum[0]);

    #pragma unroll
    for (int i = 0; i < 8; ++i)
        out_t[tid * 8 + i] = sv[i] - lse;
    if (tid == 0) {
        idx_t[0] = gidx;
        *cnt = 0;
    }
}

// ---------------------------------------------------------------------------
extern "C" void kernel_launch(void* const* d_in, const int* in_sizes, int n_in,
                              void* d_out, int out_size, void* d_ws, size_t ws_size,
                              hipStream_t stream)
{
    (void)in_sizes; (void)n_in; (void)out_size; (void)ws_size;
    const float* context = (const float*)d_in[0];
    const float* S       = (const float*)d_in[1];
    const float* enc_w1  = (const float*)d_in[2];
    const float* enc_b1  = (const float*)d_in[3];
    const float* enc_w2  = (const float*)d_in[4];
    const float* enc_b2  = (const float*)d_in[5];
    const float* w_ih    = (const float*)d_in[6];
    const float* w_hh    = (const float*)d_in[7];
    const float* b_ih    = (const float*)d_in[8];
    const float* b_hh    = (const float*)d_in[9];
    const float* att_w1  = (const float*)d_in[10];
    const float* att_b1  = (const float*)d_in[11];
    const float* att_w2  = (const float*)d_in[12];
    const float* att_b2  = (const float*)d_in[13];
    float* out = (float*)d_out;
    float* ws  = (float*)d_ws;

    // ws layout (float offsets), footprint unchanged:
    float* P      = ws;                         // 4 x 512K fp32 partials
    float* h_fp32 = ws;                         // (after P dead)
    float* c      = ws + 1048576;
    float* hid1   = ws + 2097152;
    float* preT   = ws + 3145728;
    u16* Af_hi  = (u16*)(ws + 2097152);         // dead before encoder gemm1
    u16* Af_lo  = (u16*)(ws + 2621440);
    u16* Hf_hi1 = (u16*)(ws + 0);
    u16* Hf_lo1 = (u16*)(ws + 524288);
    u16* Hf_hi0 = (u16*)(ws + 2097152);
    u16* Hf_lo0 = (u16*)(ws + 2621440);
    u16* Wf_hi  = (u16*)(ws + 3670016);
    u16* Wf_lo  = (u16*)(ws + 3801088);
    int*   cnt    = (int*)(ws + 4718592);       // [0]=cnt, [1..16]=flags
    int*   flags  = cnt + 1;
    float* rowsum = ws + 4984832;               // 1,024
    float* e_acc  = ws + 4985856;               // 4,096
    float* scores = ws + 4989952;               // 2,048
    float* WbT    = ws + 4992000;               // 65,536
    int*   idxbuf = (int*)(ws + 5057536);       // 16

    k_rowsum<<<1024, 256, 0, stream>>>(w_ih, rowsum);
    k_wbT<<<256, 256, 0, stream>>>(att_w1, WbT);
    k_packWf<<<1024, 256, 0, stream>>>(w_hh, Wf_hi, Wf_lo);

    // ---- preT = Wa @ S via MFMA bf16x3 split-K=8 (1024 blocks) ----
    k_packAf<<<4096, 256, 0, stream>>>(att_w1, Af_hi, Af_lo);
    hipMemsetAsync(P, 0, (size_t)4 * ATT_H * N_ANTES * sizeof(float), stream);
    dim3 gp(PSPLIT, N_ANTES / 64, 4);
    k_gemm_preT<<<gp, 256, 0, stream>>>(Af_hi, Af_lo, S, P);
    k_reduce4<<<(ATT_H * N_ANTES) / 256, 256, 0, stream>>>(P, preT);

    // P region dead now: clear state
    hipMemsetAsync(c, 0, (size_t)N_TRAIN * ENC * sizeof(float), stream);
    hipMemsetAsync(e_acc, 0, (size_t)MAX_LEN * ENC * sizeof(float), stream);
    hipMemsetAsync(cnt, 0, (1 + MAX_LEN) * sizeof(int), stream);

    // ---- encoder (Af dead -> hid1 region reusable) ----
    dim3 g1(N_TRAIN / 64, N_HID / 64);
    gemm_abT<true><<<g1, 256, 0, stream>>>(context, enc_w1, enc_b1, hid1,
                                           N_TRAIN, N_HID, N_FEAT, N_FEAT, N_FEAT, N_HID);
    dim3 g2(N_TRAIN / 64, ENC / 64);
    gemm_abT<false><<<g2, 256, 0, stream>>>(hid1, enc_w2, enc_b2, h_fp32,
                                            N_TRAIN, ENC, N_HID, N_HID, N_HID, ENC);
    // pack h0 fragments (overwrites hid1, dead after gemm2)
    k_packHf<<<4096, 256, 0, stream>>>(h_fp32, Hf_hi0, Hf_lo0);

    for (int t = 0; t < MAX_LEN; ++t) {
        const u16 *hr, *lr; u16 *hw, *lw;
        if ((t & 1) == 0) { hr = Hf_hi0; lr = Hf_lo0; hw = Hf_hi1; lw = Hf_lo1; }
        else              { hr = Hf_hi1; lr = Hf_lo1; hw = Hf_hi0; lw = Hf_lo0; }
        k_step<<<1088, 256, 0, stream>>>(hr, lr, hw, lw, Wf_hi, Wf_lo, c,
                                         rowsum, b_ih, b_hh, S, idxbuf, t,
                                         e_acc + t * 256,
                                         e_acc + (t > 0 ? (t - 1) * 256 : 0),
                                         preT, WbT, att_b1, att_w2, att_b2,
                                         scores,
                                         out + (t > 0 ? (size_t)(t - 1) * N_ANTES : 0),
                                         cnt, flags + t);
    }
    // final attention for t = MAX_LEN-1
    k_att<<<N_ANTES / 32, 256, 0, stream>>>(preT, e_acc + (MAX_LEN - 1) * 256,
                                            WbT, att_b1, att_w2, att_b2, scores,
                                            out + (size_t)(MAX_LEN - 1) * N_ANTES,
                                            idxbuf + (MAX_LEN - 1), cnt);
}

// Round 11
// 716.599 us; speedup vs baseline: 4.4229x; 4.4229x over previous
//
#include <hip/hip_runtime.h>
#include <hip/hip_bf16.h>
#include <math.h>

// Shapes
#define N_TRAIN 4096
#define N_FEAT  64
#define N_HID   256
#define ENC     256
#define N_ANTES 2048
#define ATT_H   256
#define MAX_LEN 16

typedef unsigned int u32;
typedef unsigned short u16;
typedef short short8 __attribute__((ext_vector_type(8)));
typedef float floatx16 __attribute__((ext_vector_type(16)));

__device__ __forceinline__ float fsig(float x)  { return 1.f / (1.f + __expf(-x)); }
__device__ __forceinline__ float ftanh(float x) { return 2.f / (1.f + __expf(-2.f * x)) - 1.f; }

// bf16 round-to-nearest-even helpers
__device__ __forceinline__ u16 f2bf(float x) {
    u32 b = __float_as_uint(x);
    return (u16)((b + 0x7FFFu + ((b >> 16) & 1u)) >> 16);
}
__device__ __forceinline__ float bf2f(u16 h) {
    return __uint_as_float(((u32)h) << 16);
}
// cheap truncation hi/lo split (residual v-hi exact in fp32)
__device__ __forceinline__ void split_bf(float v, u16& hi, u16& lo) {
    u32 b = __float_as_uint(v);
    hi = (u16)(b >> 16);
    float r = v - __uint_as_float(b & 0xFFFF0000u);
    lo = (u16)(__float_as_uint(r) >> 16);
}

// A/B fragment k-offset for v_mfma_f32_32x32x16_bf16 (2xK stacked CDNA layout):
// lane l, elem j (0..7) -> k = 4*(l>>5) + (j&3) + 8*(j>>2)
__device__ __forceinline__ int kin_of(int l, int j) {
    return ((l >> 5) << 2) + (j & 3) + ((j >> 2) << 3);
}

// ---------------------------------------------------------------------------
// Tiled GEMM: C[m,n] = act(bias[n] + sum_k A[m,k] * B[n,k]); 64x64x16 tiles.
// (encoder only)
// ---------------------------------------------------------------------------
template <bool RELU>
__global__ __launch_bounds__(256) void gemm_abT(
    const float* __restrict__ A, const float* __restrict__ B,
    const float* __restrict__ bias, float* __restrict__ C,
    int M, int N, int K, int lda, int ldb, int ldc)
{
    __shared__ __align__(16) float As[16][68];
    __shared__ __align__(16) float Bs[16][68];
    const int tid = threadIdx.x;
    const int m0 = blockIdx.x * 64, n0 = blockIdx.y * 64;
    const int tx = tid & 15, ty = tid >> 4;
    const int kl = tid & 15, rl = tid >> 4;
    float acc[4][4] = {};

    for (int k0 = 0; k0 < K; k0 += 16) {
        #pragma unroll
        for (int pp = 0; pp < 4; ++pp) {
            int r = rl + pp * 16;
            As[kl][r] = A[(size_t)(m0 + r) * lda + k0 + kl];
            Bs[kl][r] = B[(size_t)(n0 + r) * ldb + k0 + kl];
        }
        __syncthreads();
        #pragma unroll
        for (int k = 0; k < 16; ++k) {
            float4 av = *(const float4*)&As[k][ty * 4];
            float4 bv = *(const float4*)&Bs[k][tx * 4];
            float a4[4] = {av.x, av.y, av.z, av.w};
            float b4[4] = {bv.x, bv.y, bv.z, bv.w};
            #pragma unroll
            for (int i = 0; i < 4; ++i)
                #pragma unroll
                for (int j = 0; j < 4; ++j)
                    acc[i][j] = fmaf(a4[i], b4[j], acc[i][j]);
        }
        __syncthreads();
    }
    #pragma unroll
    for (int i = 0; i < 4; ++i) {
        int m = m0 + ty * 4 + i;
        #pragma unroll
        for (int j = 0; j < 4; ++j) {
            int n = n0 + tx * 4 + j;
            float v = acc[i][j] + bias[n];
            if (RELU) v = fmaxf(v, 0.f);
            C[(size_t)m * ldc + n] = v;
        }
    }
}

// ---------------------------------------------------------------------------
// rowsum[j] = sum_k w_ih[j, k]
// ---------------------------------------------------------------------------
__global__ __launch_bounds__(256) void k_rowsum(const float* __restrict__ w_ih,
                                                float* __restrict__ rowsum)
{
    __shared__ float red[256];
    const int j = blockIdx.x, tid = threadIdx.x;
    float s = 0.f;
    for (int i = tid; i < N_ANTES; i += 256) s += w_ih[(size_t)j * N_ANTES + i];
    red[tid] = s; __syncthreads();
    for (int off = 128; off > 0; off >>= 1) {
        if (tid < off) red[tid] += red[tid + off];
        __syncthreads();
    }
    if (tid == 0) rowsum[j] = red[0];
}

// ---------------------------------------------------------------------------
// WbT[k*256 + j] = att_w1[j*(N_TRAIN+ENC) + N_TRAIN + k]
// ---------------------------------------------------------------------------
__global__ __launch_bounds__(256) void k_wbT(const float* __restrict__ att_w1,
                                             float* __restrict__ WbT)
{
    int gid = blockIdx.x * 256 + threadIdx.x;  // 0..65535
    int j = gid >> 8, k = gid & 255;
    WbT[(size_t)k * 256 + j] = att_w1[(size_t)j * (N_TRAIN + ENC) + N_TRAIN + k];
}

// ---------------------------------------------------------------------------
// Pack Wa = att_w1[:, :N_TRAIN] (256x4096) into A-fragment order (bf16 hi/lo).
// ---------------------------------------------------------------------------
__global__ __launch_bounds__(256) void k_packAf(const float* __restrict__ att_w1,
                                                u16* __restrict__ Af_hi,
                                                u16* __restrict__ Af_lo)
{
    int gid = blockIdx.x * 256 + threadIdx.x;   // 0..1048575
    int j  = gid & 7;
    int l  = (gid >> 3) & 63;
    int kt = (gid >> 9) & 255;
    int mt = gid >> 17;
    int m = mt * 32 + (l & 31);
    int k = kt * 16 + kin_of(l, j);
    float v = att_w1[(size_t)m * (N_TRAIN + ENC) + k];
    u16 hi, lo; split_bf(v, hi, lo);
    Af_hi[gid] = hi;
    Af_lo[gid] = lo;
}

// ---------------------------------------------------------------------------
// preT = Wa @ S via MFMA bf16x3, split-K=8. Grid (8 kz, 32 np, 4 mq), 256 thr.
// Paired K-chunks (kz, kz+4) accumulate into buffer kz&3 via atomicAdd on
// pre-zeroed P: exactly 2 commutative fp32 adds -> deterministic.
// ---------------------------------------------------------------------------
#define PSPLIT 8
__global__ __launch_bounds__(256) void k_gemm_preT(
    const u16* __restrict__ Af_hi, const u16* __restrict__ Af_lo,
    const float* __restrict__ S, float* __restrict__ P)
{
    const int tid = threadIdx.x, lane = tid & 63, w = tid >> 6;
    const int kz = blockIdx.x;          // 0..7
    const int np = blockIdx.y;          // 0..31
    const int mq = blockIdx.z;          // 0..3
    const int mt = mq * 2 + (w & 1);    // 0..7
    const int ni = w >> 1;              // 0..1
    const int nb = np * 64 + ni * 32 + (lane & 31);
    const int kb = 4 * (lane >> 5);
    floatx16 acc = {0,0,0,0,0,0,0,0,0,0,0,0,0,0,0,0};

    const int kt_beg = kz * 32, kt_end = kt_beg + 32;
    #pragma unroll 4
    for (int kt = kt_beg; kt < kt_end; ++kt) {
        size_t ao = (((size_t)mt * 256 + kt) * 64 + lane) * 8;
        short8 ahi = *(const short8*)(Af_hi + ao);
        short8 alo = *(const short8*)(Af_lo + ao);
        short8 bhi, blo;
        #pragma unroll
        for (int j = 0; j < 8; ++j) {
            int k = kt * 16 + kb + (j & 3) + 8 * (j >> 2);
            float v = S[(size_t)k * N_ANTES + nb];
            u16 hi, lo; split_bf(v, hi, lo);
            bhi[j] = (short)hi;
            blo[j] = (short)lo;
        }
        acc = __builtin_amdgcn_mfma_f32_32x32x16_bf16(ahi, bhi, acc, 0, 0, 0);
        acc = __builtin_amdgcn_mfma_f32_32x32x16_bf16(ahi, blo, acc, 0, 0, 0);
        acc = __builtin_amdgcn_mfma_f32_32x32x16_bf16(alo, bhi, acc, 0, 0, 0);
    }

    float* Pk = P + (size_t)(kz & 3) * (ATT_H * N_ANTES);
    #pragma unroll
    for (int q = 0; q < 16; ++q) {
        int row = mt * 32 + (q & 3) + 8 * (q >> 2) + 4 * (lane >> 5);
        atomicAdd(&Pk[(size_t)row * N_ANTES + nb], acc[q]);
    }
}

__global__ __launch_bounds__(256) void k_reduce4(const float* __restrict__ P,
                                                 float* __restrict__ preT)
{
    int gid = blockIdx.x * 256 + threadIdx.x;
    const int SZ = ATT_H * N_ANTES;
    preT[gid] = (P[gid] + P[gid + SZ]) + (P[gid + 2 * SZ] + P[gid + 3 * SZ]);
}

// ---------------------------------------------------------------------------
// Pack w_hh into B-fragment order (bf16 hi/lo), gate-interleaved columns.
// ---------------------------------------------------------------------------
__global__ __launch_bounds__(256) void k_packWf(const float* __restrict__ w_hh,
                                                u16* __restrict__ Wf_hi,
                                                u16* __restrict__ Wf_lo)
{
    int gid = blockIdx.x * 256 + threadIdx.x;      // 0..262143
    int j    = gid & 7;
    int l    = (gid >> 3) & 63;
    int kt   = (gid >> 9) & 15;
    int nsub = (gid >> 13) & 1;
    int cb   = gid >> 14;
    int k  = kt * 16 + kin_of(l, j);
    int cc = nsub * 32 + (l & 31);
    int jj = cb * 16 + (cc >> 2);
    int g  = cc & 3;
    int J  = g * 256 + jj;
    float v = w_hh[(size_t)J * 256 + k];
    u16 hi = f2bf(v);
    Wf_hi[gid] = hi;
    Wf_lo[gid] = f2bf(v - bf2f(hi));
}

// ---------------------------------------------------------------------------
// Pack fp32 h into A-fragment order (bf16 hi/lo).
// ---------------------------------------------------------------------------
__global__ __launch_bounds__(256) void k_packHf(const float* __restrict__ h,
                                                u16* __restrict__ Hf_hi,
                                                u16* __restrict__ Hf_lo)
{
    int gid = blockIdx.x * 256 + threadIdx.x;      // 0..1048575
    int j  = gid & 7;
    int l  = (gid >> 3) & 63;
    int kt = (gid >> 9) & 15;
    int mt = gid >> 13;
    int m = mt * 32 + (l & 31);
    int k = kt * 16 + kin_of(l, j);
    float v = h[(size_t)m * 256 + k];
    u16 hi = f2bf(v);
    Hf_hi[gid] = hi;
    Hf_lo[gid] = f2bf(v - bf2f(hi));
}

// ---------------------------------------------------------------------------
// Fused LSTM step via MFMA (bf16x3): 32x64 tile, grid (128 rb, 16 cb),
// 256 thr, __launch_bounds__(256,8) -> 8 blocks/CU = 32 waves/CU (100% occ;
// R9's 64x64 version was 4 blocks/CU). Wave w: ni = w&1 (B slice), kh = w>>1
// (kt half). Partials land in z_lds[kh]; epilogue adds the two planes
// (deterministic). Epilogue: thread = (jj_l, rg), 2 rows each.
// ---------------------------------------------------------------------------
__global__ __launch_bounds__(256, 8) void k_zgemm(
    const u16* __restrict__ Hf_hi_r, const u16* __restrict__ Hf_lo_r,
    u16* __restrict__ Hf_hi_w, u16* __restrict__ Hf_lo_w,
    const u16* __restrict__ Wf_hi, const u16* __restrict__ Wf_lo,
    float* __restrict__ c,
    const float* __restrict__ rowsum, const float* __restrict__ b_ih,
    const float* __restrict__ b_hh, const float* __restrict__ S,
    const int* __restrict__ idx_buf, int t, float* __restrict__ e_acc_t)
{
    __shared__ __align__(16) float z_lds[2][32][68];
    __shared__ float red[256];
    const int tid  = threadIdx.x;
    const int lane = tid & 63;
    const int w    = tid >> 6;       // 0..3
    const int rb = blockIdx.x;       // 0..127 (32 rows each)
    const int cb = blockIdx.y;       // 0..15  (64 packed cols each)
    const int ni = w & 1;            // B sub-slice
    const int kh = w >> 1;           // kt half
    const int mt = rb;               // 0..127

    floatx16 acc = {0,0,0,0,0,0,0,0,0,0,0,0,0,0,0,0};
    const size_t aoff = (size_t)mt * 16 * 512 + lane * 8;
    const size_t boff = (size_t)(cb * 2 + ni) * 16 * 512 + lane * 8;

    #pragma unroll
    for (int kt = kh * 8; kt < kh * 8 + 8; ++kt) {
        short8 ahi = *(const short8*)(Hf_hi_r + aoff + kt * 512);
        short8 alo = *(const short8*)(Hf_lo_r + aoff + kt * 512);
        short8 bhi = *(const short8*)(Wf_hi   + boff + kt * 512);
        short8 blo = *(const short8*)(Wf_lo   + boff + kt * 512);
        acc = __builtin_amdgcn_mfma_f32_32x32x16_bf16(ahi, bhi, acc, 0, 0, 0);
        acc = __builtin_amdgcn_mfma_f32_32x32x16_bf16(ahi, blo, acc, 0, 0, 0);
        acc = __builtin_amdgcn_mfma_f32_32x32x16_bf16(alo, bhi, acc, 0, 0, 0);
    }

    // C/D layout (HW-verified): col = lane&31, row = (q&3)+8*(q>>2)+4*(lane>>5)
    #pragma unroll
    for (int q = 0; q < 16; ++q) {
        int row = (q & 3) + 8 * (q >> 2) + 4 * (lane >> 5);   // 0..31
        z_lds[kh][row][ni * 32 + (lane & 31)] = acc[q];
    }
    __syncthreads();

    // ---- fused gates: thread = (jj_l, rg) handles 2 rows of one enc-col ----
    const int jj_l = tid & 15, rg = tid >> 4;    // rg 0..15
    const int Jc = cb * 16 + jj_l;               // enc-dim column (0..255)
    float rs[4], bs[4];
    #pragma unroll
    for (int g = 0; g < 4; ++g) {
        int J = g * 256 + Jc;
        rs[g] = rowsum[J];
        bs[g] = b_ih[J] + b_hh[J];
    }
    const int idxp = (t > 0) ? idx_buf[t - 1] : 0;
    float esum = 0.f;
    #pragma unroll
    for (int p = 0; p < 2; ++p) {
        int r = rg * 2 + p;
        int rglob = rb * 32 + r;
        float a = (t > 0) ? S[(size_t)rglob * N_ANTES + idxp] : 1.f;
        float4 zA = *(const float4*)&z_lds[0][r][jj_l * 4];
        float4 zB = *(const float4*)&z_lds[1][r][jj_l * 4];
        float zi = (zA.x + zB.x) + fmaf(a, rs[0], bs[0]);
        float zf = (zA.y + zB.y) + fmaf(a, rs[1], bs[1]);
        float zg = (zA.z + zB.z) + fmaf(a, rs[2], bs[2]);
        float zo = (zA.w + zB.w) + fmaf(a, rs[3], bs[3]);
        size_t coff = (size_t)rglob * 256 + Jc;
        float cn = fsig(zf) * c[coff] + fsig(zi) * ftanh(zg);
        float hn = fsig(zo) * ftanh(cn);
        c[coff] = cn;
        esum += hn;
        // write h back in A-fragment order (inverse of kin_of; bijective)
        u16 hi = f2bf(hn);
        u16 lo = f2bf(hn - bf2f(hi));
        int mtw    = rglob >> 5;
        int lane_a = (rglob & 31) + 32 * ((Jc >> 2) & 1);
        int ktw    = Jc >> 4;
        int jw     = (Jc & 3) + ((Jc >> 3) & 1) * 4;
        size_t off = (((size_t)mtw * 16 + ktw) * 64 + lane_a) * 8 + jw;
        Hf_hi_w[off] = hi;
        Hf_lo_w[off] = lo;
    }
    red[tid] = esum;
    __syncthreads();
    if (tid < 16) {
        float s = 0.f;
        #pragma unroll
        for (int q = 0; q < 16; ++q) s += red[tid + q * 16];
        atomicAdd(&e_acc_t[cb * 16 + tid], s);
    }
}

// ---------------------------------------------------------------------------
// Fused attention: scores + log-softmax + argmax in ONE kernel (last-block).
// ---------------------------------------------------------------------------
__global__ __launch_bounds__(256) void k_att(
    const float* __restrict__ preT, const float* __restrict__ e_accum_t,
    const float* __restrict__ WbT, const float* __restrict__ att_b1,
    const float* __restrict__ att_w2, const float* __restrict__ att_b2,
    float* __restrict__ scores, float* __restrict__ out_t,
    int* __restrict__ idx_t, int* __restrict__ cnt)
{
    __shared__ float e_lds[256];
    __shared__ float u[256];
    __shared__ float w2s[256];
    __shared__ float red[256];
    const int tid = threadIdx.x;
    e_lds[tid] = e_accum_t[tid] * (1.f / (float)N_TRAIN);
    w2s[tid] = att_w2[tid];
    __syncthreads();

    float uacc = att_b1[tid];
    for (int k = 0; k < 256; ++k)
        uacc = fmaf(e_lds[k], WbT[(size_t)k * 256 + tid], uacc);
    u[tid] = uacc;
    __syncthreads();

    const int pl = tid & 31, jq = tid >> 5;   // 8-way j split
    const int p = blockIdx.x * 32 + pl;
    float sc = 0.f;
    #pragma unroll 4
    for (int j = jq; j < 256; j += 8) {
        float v = preT[(size_t)j * N_ANTES + p] + u[j];
        sc = fmaf(fmaxf(v, 0.f), w2s[j], sc);
    }
    red[tid] = sc;
    __syncthreads();
    if (tid < 32) {
        float s = att_b2[0];
        #pragma unroll
        for (int q = 0; q < 8; ++q) s += red[tid + q * 32];
        scores[blockIdx.x * 32 + tid] = s;
    }

    // ---- last-block handshake ----
    __threadfence();
    __syncthreads();
    __shared__ int is_last;
    if (tid == 0)
        is_last = (atomicAdd(cnt, 1) == (int)gridDim.x - 1);
    __syncthreads();
    if (!is_last) return;
    __threadfence();

    // ---- phase 2: log-softmax + argmax over 2048 scores (one block) ----
    __shared__ float smax[256];
    __shared__ int   sidx[256];
    __shared__ float ssum[256];

    float sv[8];
    #pragma unroll
    for (int i = 0; i < 8; ++i) sv[i] = scores[tid * 8 + i];

    float lmax = -INFINITY; int lidx = 0;
    #pragma unroll
    for (int i = 0; i < 8; ++i)
        if (sv[i] > lmax) { lmax = sv[i]; lidx = tid * 8 + i; }
    smax[tid] = lmax; sidx[tid] = lidx;
    __syncthreads();
    for (int off = 128; off > 0; off >>= 1) {
        if (tid < off) {
            float ov = smax[tid + off]; int oi = sidx[tid + off];
            if (ov > smax[tid] || (ov == smax[tid] && oi < sidx[tid])) {
                smax[tid] = ov; sidx[tid] = oi;
            }
        }
        __syncthreads();
    }
    const float gmax = smax[0];
    const int gidx = sidx[0];

    float lsum = 0.f;
    #pragma unroll
    for (int i = 0; i < 8; ++i) lsum += __expf(sv[i] - gmax);
    ssum[tid] = lsum;
    __syncthreads();
    for (int off = 128; off > 0; off >>= 1) {
        if (tid < off) ssum[tid] += ssum[tid + off];
        __syncthreads();
    }
    const float lse = gmax + logf(ssum[0]);

    #pragma unroll
    for (int i = 0; i < 8; ++i)
        out_t[tid * 8 + i] = sv[i] - lse;
    if (tid == 0) {
        idx_t[0] = gidx;
        *cnt = 0;
    }
}

// ---------------------------------------------------------------------------
extern "C" void kernel_launch(void* const* d_in, const int* in_sizes, int n_in,
                              void* d_out, int out_size, void* d_ws, size_t ws_size,
                              hipStream_t stream)
{
    (void)in_sizes; (void)n_in; (void)out_size; (void)ws_size;
    const float* context = (const float*)d_in[0];
    const float* S       = (const float*)d_in[1];
    const float* enc_w1  = (const float*)d_in[2];
    const float* enc_b1  = (const float*)d_in[3];
    const float* enc_w2  = (const float*)d_in[4];
    const float* enc_b2  = (const float*)d_in[5];
    const float* w_ih    = (const float*)d_in[6];
    const float* w_hh    = (const float*)d_in[7];
    const float* b_ih    = (const float*)d_in[8];
    const float* b_hh    = (const float*)d_in[9];
    const float* att_w1  = (const float*)d_in[10];
    const float* att_b1  = (const float*)d_in[11];
    const float* att_w2  = (const float*)d_in[12];
    const float* att_b2  = (const float*)d_in[13];
    float* out = (float*)d_out;
    float* ws  = (float*)d_ws;

    // ws layout (float offsets), footprint unchanged:
    float* P      = ws;                         // 4 x 512K fp32 partials
    float* h_fp32 = ws;                         // (after P dead)
    float* c      = ws + 1048576;
    float* hid1   = ws + 2097152;
    float* preT   = ws + 3145728;
    u16* Af_hi  = (u16*)(ws + 2097152);         // dead before encoder gemm1
    u16* Af_lo  = (u16*)(ws + 2621440);
    u16* Hf_hi1 = (u16*)(ws + 0);
    u16* Hf_lo1 = (u16*)(ws + 524288);
    u16* Hf_hi0 = (u16*)(ws + 2097152);
    u16* Hf_lo0 = (u16*)(ws + 2621440);
    u16* Wf_hi  = (u16*)(ws + 3670016);
    u16* Wf_lo  = (u16*)(ws + 3801088);
    int*   cnt    = (int*)(ws + 4718592);
    float* rowsum = ws + 4984832;               // 1,024
    float* e_acc  = ws + 4985856;               // 4,096
    float* scores = ws + 4989952;               // 2,048
    float* WbT    = ws + 4992000;               // 65,536
    int*   idxbuf = (int*)(ws + 5057536);       // 16

    k_rowsum<<<1024, 256, 0, stream>>>(w_ih, rowsum);
    k_wbT<<<256, 256, 0, stream>>>(att_w1, WbT);
    k_packWf<<<1024, 256, 0, stream>>>(w_hh, Wf_hi, Wf_lo);

    // ---- preT = Wa @ S via MFMA bf16x3 split-K=8 (1024 blocks) ----
    k_packAf<<<4096, 256, 0, stream>>>(att_w1, Af_hi, Af_lo);
    hipMemsetAsync(P, 0, (size_t)4 * ATT_H * N_ANTES * sizeof(float), stream);
    dim3 gp(PSPLIT, N_ANTES / 64, 4);
    k_gemm_preT<<<gp, 256, 0, stream>>>(Af_hi, Af_lo, S, P);
    k_reduce4<<<(ATT_H * N_ANTES) / 256, 256, 0, stream>>>(P, preT);

    // P region dead now: clear state
    hipMemsetAsync(c, 0, (size_t)N_TRAIN * ENC * sizeof(float), stream);
    hipMemsetAsync(e_acc, 0, (size_t)MAX_LEN * ENC * sizeof(float), stream);
    hipMemsetAsync(cnt, 0, sizeof(int), stream);

    // ---- encoder (Af dead -> hid1 region reusable) ----
    dim3 g1(N_TRAIN / 64, N_HID / 64);
    gemm_abT<true><<<g1, 256, 0, stream>>>(context, enc_w1, enc_b1, hid1,
                                           N_TRAIN, N_HID, N_FEAT, N_FEAT, N_FEAT, N_HID);
    dim3 g2(N_TRAIN / 64, ENC / 64);
    gemm_abT<false><<<g2, 256, 0, stream>>>(hid1, enc_w2, enc_b2, h_fp32,
                                            N_TRAIN, ENC, N_HID, N_HID, N_HID, ENC);
    // pack h0 fragments (overwrites hid1, dead after gemm2)
    k_packHf<<<4096, 256, 0, stream>>>(h_fp32, Hf_hi0, Hf_lo0);

    dim3 gz(128, 16);
    for (int t = 0; t < MAX_LEN; ++t) {
        const u16 *hr, *lr; u16 *hw, *lw;
        if ((t & 1) == 0) { hr = Hf_hi0; lr = Hf_lo0; hw = Hf_hi1; lw = Hf_lo1; }
        else              { hr = Hf_hi1; lr = Hf_lo1; hw = Hf_hi0; lw = Hf_lo0; }
        k_zgemm<<<gz, 256, 0, stream>>>(hr, lr, hw, lw, Wf_hi, Wf_lo, c,
                                        rowsum, b_ih, b_hh, S, idxbuf, t,
                                        e_acc + t * 256);
        k_att<<<N_ANTES / 32, 256, 0, stream>>>(preT, e_acc + t * 256, WbT,
                                                att_b1, att_w2, att_b2, scores,
                                                out + t * N_ANTES, idxbuf + t, cnt);
    }
}

// Round 12
// 706.217 us; speedup vs baseline: 4.4879x; 1.0147x over previous
//
#include <hip/hip_runtime.h>
#include <hip/hip_bf16.h>
#include <math.h>

// Shapes
#define N_TRAIN 4096
#define N_FEAT  64
#define N_HID   256
#define ENC     256
#define N_ANTES 2048
#define ATT_H   256
#define MAX_LEN 16

typedef unsigned int u32;
typedef unsigned short u16;
typedef short short8 __attribute__((ext_vector_type(8)));
typedef float floatx16 __attribute__((ext_vector_type(16)));

__device__ __forceinline__ float fsig(float x)  { return 1.f / (1.f + __expf(-x)); }
__device__ __forceinline__ float ftanh(float x) { return 2.f / (1.f + __expf(-2.f * x)) - 1.f; }

// bf16 round-to-nearest-even helpers
__device__ __forceinline__ u16 f2bf(float x) {
    u32 b = __float_as_uint(x);
    return (u16)((b + 0x7FFFu + ((b >> 16) & 1u)) >> 16);
}
__device__ __forceinline__ float bf2f(u16 h) {
    return __uint_as_float(((u32)h) << 16);
}
// cheap truncation hi/lo split (residual v-hi exact in fp32)
__device__ __forceinline__ void split_bf(float v, u16& hi, u16& lo) {
    u32 b = __float_as_uint(v);
    hi = (u16)(b >> 16);
    float r = v - __uint_as_float(b & 0xFFFF0000u);
    lo = (u16)(__float_as_uint(r) >> 16);
}

// A/B fragment k-offset for v_mfma_f32_32x32x16_bf16 (2xK stacked CDNA layout):
// lane l, elem j (0..7) -> k = 4*(l>>5) + (j&3) + 8*(j>>2)
__device__ __forceinline__ int kin_of(int l, int j) {
    return ((l >> 5) << 2) + (j & 3) + ((j >> 2) << 3);
}

// ---------------------------------------------------------------------------
// Tiled GEMM: C[m,n] = act(bias[n] + sum_k A[m,k] * B[n,k]); 64x64x16 tiles.
// (encoder only)
// ---------------------------------------------------------------------------
template <bool RELU>
__global__ __launch_bounds__(256) void gemm_abT(
    const float* __restrict__ A, const float* __restrict__ B,
    const float* __restrict__ bias, float* __restrict__ C,
    int M, int N, int K, int lda, int ldb, int ldc)
{
    __shared__ __align__(16) float As[16][68];
    __shared__ __align__(16) float Bs[16][68];
    const int tid = threadIdx.x;
    const int m0 = blockIdx.x * 64, n0 = blockIdx.y * 64;
    const int tx = tid & 15, ty = tid >> 4;
    const int kl = tid & 15, rl = tid >> 4;
    float acc[4][4] = {};

    for (int k0 = 0; k0 < K; k0 += 16) {
        #pragma unroll
        for (int pp = 0; pp < 4; ++pp) {
            int r = rl + pp * 16;
            As[kl][r] = A[(size_t)(m0 + r) * lda + k0 + kl];
            Bs[kl][r] = B[(size_t)(n0 + r) * ldb + k0 + kl];
        }
        __syncthreads();
        #pragma unroll
        for (int k = 0; k < 16; ++k) {
            float4 av = *(const float4*)&As[k][ty * 4];
            float4 bv = *(const float4*)&Bs[k][tx * 4];
            float a4[4] = {av.x, av.y, av.z, av.w};
            float b4[4] = {bv.x, bv.y, bv.z, bv.w};
            #pragma unroll
            for (int i = 0; i < 4; ++i)
                #pragma unroll
                for (int j = 0; j < 4; ++j)
                    acc[i][j] = fmaf(a4[i], b4[j], acc[i][j]);
        }
        __syncthreads();
    }
    #pragma unroll
    for (int i = 0; i < 4; ++i) {
        int m = m0 + ty * 4 + i;
        #pragma unroll
        for (int j = 0; j < 4; ++j) {
            int n = n0 + tx * 4 + j;
            float v = acc[i][j] + bias[n];
            if (RELU) v = fmaxf(v, 0.f);
            C[(size_t)m * ldc + n] = v;
        }
    }
}

// ---------------------------------------------------------------------------
// rowsum[j] = sum_k w_ih[j, k]
// ---------------------------------------------------------------------------
__global__ __launch_bounds__(256) void k_rowsum(const float* __restrict__ w_ih,
                                                float* __restrict__ rowsum)
{
    __shared__ float red[256];
    const int j = blockIdx.x, tid = threadIdx.x;
    float s = 0.f;
    for (int i = tid; i < N_ANTES; i += 256) s += w_ih[(size_t)j * N_ANTES + i];
    red[tid] = s; __syncthreads();
    for (int off = 128; off > 0; off >>= 1) {
        if (tid < off) red[tid] += red[tid + off];
        __syncthreads();
    }
    if (tid == 0) rowsum[j] = red[0];
}

// ---------------------------------------------------------------------------
// WbT[k*256 + j] = att_w1[j*(N_TRAIN+ENC) + N_TRAIN + k]
// ---------------------------------------------------------------------------
__global__ __launch_bounds__(256) void k_wbT(const float* __restrict__ att_w1,
                                             float* __restrict__ WbT)
{
    int gid = blockIdx.x * 256 + threadIdx.x;  // 0..65535
    int j = gid >> 8, k = gid & 255;
    WbT[(size_t)k * 256 + j] = att_w1[(size_t)j * (N_TRAIN + ENC) + N_TRAIN + k];
}

// ---------------------------------------------------------------------------
// Pack Wa = att_w1[:, :N_TRAIN] (256x4096) into A-fragment order (bf16 hi/lo).
// ---------------------------------------------------------------------------
__global__ __launch_bounds__(256) void k_packAf(const float* __restrict__ att_w1,
                                                u16* __restrict__ Af_hi,
                                                u16* __restrict__ Af_lo)
{
    int gid = blockIdx.x * 256 + threadIdx.x;   // 0..1048575
    int j  = gid & 7;
    int l  = (gid >> 3) & 63;
    int kt = (gid >> 9) & 255;
    int mt = gid >> 17;
    int m = mt * 32 + (l & 31);
    int k = kt * 16 + kin_of(l, j);
    float v = att_w1[(size_t)m * (N_TRAIN + ENC) + k];
    u16 hi, lo; split_bf(v, hi, lo);
    Af_hi[gid] = hi;
    Af_lo[gid] = lo;
}

// ---------------------------------------------------------------------------
// preT = Wa @ S via MFMA bf16x3, split-K=16. Grid (16 kz, 32 np, 4 mq),
// 256 thr -> 2048 blocks = 8 blocks/CU (R9's 1024 was 4/CU, occ 30%).
// K-chunks with equal kz&3 accumulate into buffer kz&3 via atomicAdd on
// pre-zeroed P (4 commutative fp32 adds; ~1e-6 run wiggle, harmless).
// ---------------------------------------------------------------------------
#define PSPLIT 16
__global__ __launch_bounds__(256) void k_gemm_preT(
    const u16* __restrict__ Af_hi, const u16* __restrict__ Af_lo,
    const float* __restrict__ S, float* __restrict__ P)
{
    const int tid = threadIdx.x, lane = tid & 63, w = tid >> 6;
    const int kz = blockIdx.x;          // 0..15
    const int np = blockIdx.y;          // 0..31
    const int mq = blockIdx.z;          // 0..3
    const int mt = mq * 2 + (w & 1);    // 0..7
    const int ni = w >> 1;              // 0..1
    const int nb = np * 64 + ni * 32 + (lane & 31);
    const int kb = 4 * (lane >> 5);
    floatx16 acc = {0,0,0,0,0,0,0,0,0,0,0,0,0,0,0,0};

    const int kt_beg = kz * 16, kt_end = kt_beg + 16;
    #pragma unroll 4
    for (int kt = kt_beg; kt < kt_end; ++kt) {
        size_t ao = (((size_t)mt * 256 + kt) * 64 + lane) * 8;
        short8 ahi = *(const short8*)(Af_hi + ao);
        short8 alo = *(const short8*)(Af_lo + ao);
        short8 bhi, blo;
        #pragma unroll
        for (int j = 0; j < 8; ++j) {
            int k = kt * 16 + kb + (j & 3) + 8 * (j >> 2);
            float v = S[(size_t)k * N_ANTES + nb];
            u16 hi, lo; split_bf(v, hi, lo);
            bhi[j] = (short)hi;
            blo[j] = (short)lo;
        }
        acc = __builtin_amdgcn_mfma_f32_32x32x16_bf16(ahi, bhi, acc, 0, 0, 0);
        acc = __builtin_amdgcn_mfma_f32_32x32x16_bf16(ahi, blo, acc, 0, 0, 0);
        acc = __builtin_amdgcn_mfma_f32_32x32x16_bf16(alo, bhi, acc, 0, 0, 0);
    }

    float* Pk = P + (size_t)(kz & 3) * (ATT_H * N_ANTES);
    #pragma unroll
    for (int q = 0; q < 16; ++q) {
        int row = mt * 32 + (q & 3) + 8 * (q >> 2) + 4 * (lane >> 5);
        atomicAdd(&Pk[(size_t)row * N_ANTES + nb], acc[q]);
    }
}

__global__ __launch_bounds__(256) void k_reduce4(const float* __restrict__ P,
                                                 float* __restrict__ preT)
{
    int gid = blockIdx.x * 256 + threadIdx.x;
    const int SZ = ATT_H * N_ANTES;
    preT[gid] = (P[gid] + P[gid + SZ]) + (P[gid + 2 * SZ] + P[gid + 3 * SZ]);
}

// ---------------------------------------------------------------------------
// Pack w_hh into B-fragment order (bf16 hi/lo), gate-interleaved columns.
// ---------------------------------------------------------------------------
__global__ __launch_bounds__(256) void k_packWf(const float* __restrict__ w_hh,
                                                u16* __restrict__ Wf_hi,
                                                u16* __restrict__ Wf_lo)
{
    int gid = blockIdx.x * 256 + threadIdx.x;      // 0..262143
    int j    = gid & 7;
    int l    = (gid >> 3) & 63;
    int kt   = (gid >> 9) & 15;
    int nsub = (gid >> 13) & 1;
    int cb   = gid >> 14;
    int k  = kt * 16 + kin_of(l, j);
    int cc = nsub * 32 + (l & 31);
    int jj = cb * 16 + (cc >> 2);
    int g  = cc & 3;
    int J  = g * 256 + jj;
    float v = w_hh[(size_t)J * 256 + k];
    u16 hi = f2bf(v);
    Wf_hi[gid] = hi;
    Wf_lo[gid] = f2bf(v - bf2f(hi));
}

// ---------------------------------------------------------------------------
// Pack fp32 h into A-fragment order (bf16 hi/lo).
// ---------------------------------------------------------------------------
__global__ __launch_bounds__(256) void k_packHf(const float* __restrict__ h,
                                                u16* __restrict__ Hf_hi,
                                                u16* __restrict__ Hf_lo)
{
    int gid = blockIdx.x * 256 + threadIdx.x;      // 0..1048575
    int j  = gid & 7;
    int l  = (gid >> 3) & 63;
    int kt = (gid >> 9) & 15;
    int mt = gid >> 13;
    int m = mt * 32 + (l & 31);
    int k = kt * 16 + kin_of(l, j);
    float v = h[(size_t)m * 256 + k];
    u16 hi = f2bf(v);
    Hf_hi[gid] = hi;
    Hf_lo[gid] = f2bf(v - bf2f(hi));
}

// ---------------------------------------------------------------------------
// Fused LSTM step via MFMA (bf16x3): 64x64 tile, grid (64 rb, 16 cb), 256 thr
// (the R9 config, 694 us verified). NEW: h write-back staged in LDS and
// emitted as coalesced 16B short8 stores (2 contiguous 1KB fragment tiles
// per block, mtw=2rb+{0,1}, ktw=cb) instead of 2M scattered 2B stores.
// Values bit-identical to R9 (same f2bf/residual math).
// ---------------------------------------------------------------------------
__global__ __launch_bounds__(256) void k_zgemm(
    const u16* __restrict__ Hf_hi_r, const u16* __restrict__ Hf_lo_r,
    u16* __restrict__ Hf_hi_w, u16* __restrict__ Hf_lo_w,
    const u16* __restrict__ Wf_hi, const u16* __restrict__ Wf_lo,
    float* __restrict__ c,
    const float* __restrict__ rowsum, const float* __restrict__ b_ih,
    const float* __restrict__ b_hh, const float* __restrict__ S,
    const int* __restrict__ idx_buf, int t, float* __restrict__ e_acc_t)
{
    __shared__ __align__(16) float z_lds[64][68];
    __shared__ u32 hstage[2][64][8];               // 4 KB
    __shared__ float red[256];
    const int tid  = threadIdx.x;
    const int lane = tid & 63;
    const int w    = tid >> 6;       // 0..3
    const int rb = blockIdx.x;       // 0..63  (64 rows each)
    const int cb = blockIdx.y;       // 0..15  (64 packed cols each)
    const int mt = rb * 2 + (w & 1); // 0..127
    const int ni = w >> 1;           // 0..1

    floatx16 acc = {0,0,0,0,0,0,0,0,0,0,0,0,0,0,0,0};
    const size_t aoff = (size_t)mt * 16 * 512 + lane * 8;
    const size_t boff = (size_t)(cb * 2 + ni) * 16 * 512 + lane * 8;

    #pragma unroll 4
    for (int kt = 0; kt < 16; ++kt) {
        short8 ahi = *(const short8*)(Hf_hi_r + aoff + kt * 512);
        short8 alo = *(const short8*)(Hf_lo_r + aoff + kt * 512);
        short8 bhi = *(const short8*)(Wf_hi   + boff + kt * 512);
        short8 blo = *(const short8*)(Wf_lo   + boff + kt * 512);
        acc = __builtin_amdgcn_mfma_f32_32x32x16_bf16(ahi, bhi, acc, 0, 0, 0);
        acc = __builtin_amdgcn_mfma_f32_32x32x16_bf16(ahi, blo, acc, 0, 0, 0);
        acc = __builtin_amdgcn_mfma_f32_32x32x16_bf16(alo, bhi, acc, 0, 0, 0);
    }

    // C/D layout (HW-verified): col = lane&31, row = (q&3)+8*(q>>2)+4*(lane>>5)
    #pragma unroll
    for (int q = 0; q < 16; ++q) {
        int row = (w & 1) * 32 + (q & 3) + 8 * (q >> 2) + 4 * (lane >> 5);
        z_lds[row][ni * 32 + (lane & 31)] = acc[q];
    }
    __syncthreads();

    // ---- fused gates: thread = (jj_l, rg) handles 4 rows of one enc-col ----
    const int jj_l = tid & 15, rg = tid >> 4;
    const int Jc = cb * 16 + jj_l;           // enc-dim column (0..255)
    float rs[4], bs[4];
    #pragma unroll
    for (int g = 0; g < 4; ++g) {
        int J = g * 256 + Jc;
        rs[g] = rowsum[J];
        bs[g] = b_ih[J] + b_hh[J];
    }
    const int idxp = (t > 0) ? idx_buf[t - 1] : 0;
    // fragment sub-coords from Jc (ktw == cb; la-bit/jw from jj_l)
    const int laJ = 32 * ((jj_l >> 2) & 1);
    const int jw  = (jj_l & 3) + ((jj_l >> 3) & 1) * 4;
    float esum = 0.f;
    #pragma unroll
    for (int p = 0; p < 4; ++p) {
        int r = rg * 4 + p;
        int rglob = rb * 64 + r;
        float a = (t > 0) ? S[(size_t)rglob * N_ANTES + idxp] : 1.f;
        float4 z4 = *(const float4*)&z_lds[r][jj_l * 4];
        float zi = z4.x + fmaf(a, rs[0], bs[0]);
        float zf = z4.y + fmaf(a, rs[1], bs[1]);
        float zg = z4.z + fmaf(a, rs[2], bs[2]);
        float zo = z4.w + fmaf(a, rs[3], bs[3]);
        size_t coff = (size_t)rglob * 256 + Jc;
        float cn = fsig(zf) * c[coff] + fsig(zi) * ftanh(zg);
        float hn = fsig(zo) * ftanh(cn);
        c[coff] = cn;
        esum += hn;
        // stage h (A-fragment coords) in LDS; coalesced write after barrier
        u16 hi = f2bf(hn);
        u16 lo = f2bf(hn - bf2f(hi));
        int tIdx = (rglob >> 5) & 1;             // which of the 2 tiles
        int la   = (rglob & 31) + laJ;           // fragment lane 0..63
        hstage[tIdx][la][jw] = ((u32)hi << 16) | (u32)lo;
    }
    red[tid] = esum;
    __syncthreads();

    // ---- coalesced Hf write: 128 threads, 16B short8 stores ----
    if (tid < 128) {
        int tile = tid >> 6, la = tid & 63;
        int mtw = rb * 2 + tile;
        size_t base = (((size_t)mtw * 16 + cb) * 64 + la) * 8;
        short8 vh, vl;
        #pragma unroll
        for (int j = 0; j < 8; ++j) {
            u32 x = hstage[tile][la][j];
            vh[j] = (short)(x >> 16);
            vl[j] = (short)(x & 0xFFFFu);
        }
        *(short8*)(Hf_hi_w + base) = vh;
        *(short8*)(Hf_lo_w + base) = vl;
    }
    if (tid < 16) {
        float s = 0.f;
        #pragma unroll
        for (int q = 0; q < 16; ++q) s += red[tid + q * 16];
        atomicAdd(&e_acc_t[cb * 16 + tid], s);
    }
}

// ---------------------------------------------------------------------------
// Fused attention: scores + log-softmax + argmax in ONE kernel (last-block).
// ---------------------------------------------------------------------------
__global__ __launch_bounds__(256) void k_att(
    const float* __restrict__ preT, const float* __restrict__ e_accum_t,
    const float* __restrict__ WbT, const float* __restrict__ att_b1,
    const float* __restrict__ att_w2, const float* __restrict__ att_b2,
    float* __restrict__ scores, float* __restrict__ out_t,
    int* __restrict__ idx_t, int* __restrict__ cnt)
{
    __shared__ float e_lds[256];
    __shared__ float u[256];
    __shared__ float w2s[256];
    __shared__ float red[256];
    const int tid = threadIdx.x;
    e_lds[tid] = e_accum_t[tid] * (1.f / (float)N_TRAIN);
    w2s[tid] = att_w2[tid];
    __syncthreads();

    float uacc = att_b1[tid];
    for (int k = 0; k < 256; ++k)
        uacc = fmaf(e_lds[k], WbT[(size_t)k * 256 + tid], uacc);
    u[tid] = uacc;
    __syncthreads();

    const int pl = tid & 31, jq = tid >> 5;   // 8-way j split
    const int p = blockIdx.x * 32 + pl;
    float sc = 0.f;
    #pragma unroll 4
    for (int j = jq; j < 256; j += 8) {
        float v = preT[(size_t)j * N_ANTES + p] + u[j];
        sc = fmaf(fmaxf(v, 0.f), w2s[j], sc);
    }
    red[tid] = sc;
    __syncthreads();
    if (tid < 32) {
        float s = att_b2[0];
        #pragma unroll
        for (int q = 0; q < 8; ++q) s += red[tid + q * 32];
        scores[blockIdx.x * 32 + tid] = s;
    }

    // ---- last-block handshake ----
    __threadfence();
    __syncthreads();
    __shared__ int is_last;
    if (tid == 0)
        is_last = (atomicAdd(cnt, 1) == (int)gridDim.x - 1);
    __syncthreads();
    if (!is_last) return;
    __threadfence();

    // ---- phase 2: log-softmax + argmax over 2048 scores (one block) ----
    __shared__ float smax[256];
    __shared__ int   sidx[256];
    __shared__ float ssum[256];

    float sv[8];
    #pragma unroll
    for (int i = 0; i < 8; ++i) sv[i] = scores[tid * 8 + i];

    float lmax = -INFINITY; int lidx = 0;
    #pragma unroll
    for (int i = 0; i < 8; ++i)
        if (sv[i] > lmax) { lmax = sv[i]; lidx = tid * 8 + i; }
    smax[tid] = lmax; sidx[tid] = lidx;
    __syncthreads();
    for (int off = 128; off > 0; off >>= 1) {
        if (tid < off) {
            float ov = smax[tid + off]; int oi = sidx[tid + off];
            if (ov > smax[tid] || (ov == smax[tid] && oi < sidx[tid])) {
                smax[tid] = ov; sidx[tid] = oi;
            }
        }
        __syncthreads();
    }
    const float gmax = smax[0];
    const int gidx = sidx[0];

    float lsum = 0.f;
    #pragma unroll
    for (int i = 0; i < 8; ++i) lsum += __expf(sv[i] - gmax);
    ssum[tid] = lsum;
    __syncthreads();
    for (int off = 128; off > 0; off >>= 1) {
        if (tid < off) ssum[tid] += ssum[tid + off];
        __syncthreads();
    }
    const float lse = gmax + logf(ssum[0]);

    #pragma unroll
    for (int i = 0; i < 8; ++i)
        out_t[tid * 8 + i] = sv[i] - lse;
    if (tid == 0) {
        idx_t[0] = gidx;
        *cnt = 0;
    }
}

// ---------------------------------------------------------------------------
extern "C" void kernel_launch(void* const* d_in, const int* in_sizes, int n_in,
                              void* d_out, int out_size, void* d_ws, size_t ws_size,
                              hipStream_t stream)
{
    (void)in_sizes; (void)n_in; (void)out_size; (void)ws_size;
    const float* context = (const float*)d_in[0];
    const float* S       = (const float*)d_in[1];
    const float* enc_w1  = (const float*)d_in[2];
    const float* enc_b1  = (const float*)d_in[3];
    const float* enc_w2  = (const float*)d_in[4];
    const float* enc_b2  = (const float*)d_in[5];
    const float* w_ih    = (const float*)d_in[6];
    const float* w_hh    = (const float*)d_in[7];
    const float* b_ih    = (const float*)d_in[8];
    const float* b_hh    = (const float*)d_in[9];
    const float* att_w1  = (const float*)d_in[10];
    const float* att_b1  = (const float*)d_in[11];
    const float* att_w2  = (const float*)d_in[12];
    const float* att_b2  = (const float*)d_in[13];
    float* out = (float*)d_out;
    float* ws  = (float*)d_ws;

    // ws layout (float offsets), footprint unchanged:
    float* P      = ws;                         // 4 x 512K fp32 partials
    float* h_fp32 = ws;                         // (after P dead)
    float* c      = ws + 1048576;
    float* hid1   = ws + 2097152;
    float* preT   = ws + 3145728;
    u16* Af_hi  = (u16*)(ws + 2097152);         // dead before encoder gemm1
    u16* Af_lo  = (u16*)(ws + 2621440);
    u16* Hf_hi1 = (u16*)(ws + 0);
    u16* Hf_lo1 = (u16*)(ws + 524288);
    u16* Hf_hi0 = (u16*)(ws + 2097152);
    u16* Hf_lo0 = (u16*)(ws + 2621440);
    u16* Wf_hi  = (u16*)(ws + 3670016);
    u16* Wf_lo  = (u16*)(ws + 3801088);
    int*   cnt    = (int*)(ws + 4718592);
    float* rowsum = ws + 4984832;               // 1,024
    float* e_acc  = ws + 4985856;               // 4,096
    float* scores = ws + 4989952;               // 2,048
    float* WbT    = ws + 4992000;               // 65,536
    int*   idxbuf = (int*)(ws + 5057536);       // 16

    k_rowsum<<<1024, 256, 0, stream>>>(w_ih, rowsum);
    k_wbT<<<256, 256, 0, stream>>>(att_w1, WbT);
    k_packWf<<<1024, 256, 0, stream>>>(w_hh, Wf_hi, Wf_lo);

    // ---- preT = Wa @ S via MFMA bf16x3 split-K=16 (2048 blocks) ----
    k_packAf<<<4096, 256, 0, stream>>>(att_w1, Af_hi, Af_lo);
    hipMemsetAsync(P, 0, (size_t)4 * ATT_H * N_ANTES * sizeof(float), stream);
    dim3 gp(PSPLIT, N_ANTES / 64, 4);
    k_gemm_preT<<<gp, 256, 0, stream>>>(Af_hi, Af_lo, S, P);
    k_reduce4<<<(ATT_H * N_ANTES) / 256, 256, 0, stream>>>(P, preT);

    // P region dead now: clear state
    hipMemsetAsync(c, 0, (size_t)N_TRAIN * ENC * sizeof(float), stream);
    hipMemsetAsync(e_acc, 0, (size_t)MAX_LEN * ENC * sizeof(float), stream);
    hipMemsetAsync(cnt, 0, sizeof(int), stream);

    // ---- encoder (Af dead -> hid1 region reusable) ----
    dim3 g1(N_TRAIN / 64, N_HID / 64);
    gemm_abT<true><<<g1, 256, 0, stream>>>(context, enc_w1, enc_b1, hid1,
                                           N_TRAIN, N_HID, N_FEAT, N_FEAT, N_FEAT, N_HID);
    dim3 g2(N_TRAIN / 64, ENC / 64);
    gemm_abT<false><<<g2, 256, 0, stream>>>(hid1, enc_w2, enc_b2, h_fp32,
                                            N_TRAIN, ENC, N_HID, N_HID, N_HID, ENC);
    // pack h0 fragments (overwrites hid1, dead after gemm2)
    k_packHf<<<4096, 256, 0, stream>>>(h_fp32, Hf_hi0, Hf_lo0);

    dim3 gz(64, 16);
    for (int t = 0; t < MAX_LEN; ++t) {
        const u16 *hr, *lr; u16 *hw, *lw;
        if ((t & 1) == 0) { hr = Hf_hi0; lr = Hf_lo0; hw = Hf_hi1; lw = Hf_lo1; }
        else              { hr = Hf_hi1; lr = Hf_lo1; hw = Hf_hi0; lw = Hf_lo0; }
        k_zgemm<<<gz, 256, 0, stream>>>(hr, lr, hw, lw, Wf_hi, Wf_lo, c,
                                        rowsum, b_ih, b_hh, S, idxbuf, t,
                                        e_acc + t * 256);
        k_att<<<N_ANTES / 32, 256, 0, stream>>>(preT, e_acc + t * 256, WbT,
                                                att_b1, att_w2, att_b2, scores,
                                                out + t * N_ANTES, idxbuf + t, cnt);
    }
}